// Round 15
// baseline (85.235 us; speedup 1.0000x reference)
//
#include <hip/hip_runtime.h>
#include <hip/hip_bf16.h>

#define NN 2048
#define BB 8
#define LL 64
#define ADA 16
#define DH 16
#define HB 32
#define KT 2048  // GCN GEMM total K = ADA*2*LL

typedef __attribute__((ext_vector_type(4))) short bf16x4;
typedef __attribute__((ext_vector_type(4))) float f32x4;
typedef __attribute__((ext_vector_type(8))) unsigned short ushort8v;
typedef _Float16 half_t;
typedef __attribute__((ext_vector_type(2))) _Float16 halfx2;
typedef __attribute__((ext_vector_type(4))) _Float16 halfx4;
typedef __attribute__((ext_vector_type(8))) _Float16 halfx8;

// __has_builtin(__builtin_amdgcn_mfma_*) is FALSE on the host pass of hipcc's
// dual compile -> guard with __HIP_DEVICE_COMPILE__, parse-only dummy on host.
#if defined(__HIP_DEVICE_COMPILE__)
#if __has_builtin(__builtin_amdgcn_mfma_f32_16x16x16bf16_1k)
#define MFMA16(a, b, c) __builtin_amdgcn_mfma_f32_16x16x16bf16_1k(a, b, c, 0, 0, 0)
#elif __has_builtin(__builtin_amdgcn_mfma_f32_16x16x16_bf16)
#define MFMA16(a, b, c) __builtin_amdgcn_mfma_f32_16x16x16_bf16(a, b, c, 0, 0, 0)
#else
#error "no 16x16x16 bf16 mfma builtin on device"
#endif
#if __has_builtin(__builtin_amdgcn_mfma_f32_16x16x16f16)
#define MFMA16H(a, b, c) __builtin_amdgcn_mfma_f32_16x16x16f16(a, b, c, 0, 0, 0)
#elif __has_builtin(__builtin_amdgcn_mfma_f32_16x16x16_f16)
#define MFMA16H(a, b, c) __builtin_amdgcn_mfma_f32_16x16x16_f16(a, b, c, 0, 0, 0)
#else
#error "no 16x16x16 f16 mfma builtin on device"
#endif
#if __has_builtin(__builtin_amdgcn_exp2f)
#define EXP2F(x) __builtin_amdgcn_exp2f(x)
#else
#define EXP2F(x) exp2f(x)
#endif
#else
#define MFMA16(a, b, c) (c)
#define MFMA16H(a, b, c) (c)
#define EXP2F(x) exp2f(x)
#endif

__device__ inline halfx2 cvt_pk2(float a, float b) {
#if defined(__HIP_DEVICE_COMPILE__) && __has_builtin(__builtin_amdgcn_cvt_pkrtz)
  auto r = __builtin_amdgcn_cvt_pkrtz(a, b);
  return __builtin_bit_cast(halfx2, r);
#else
  halfx2 r;
  r[0] = (_Float16)a;
  r[1] = (_Float16)b;
  return r;
#endif
}

__device__ inline unsigned short f2bf(float x) {
  __hip_bfloat16 h = __float2bfloat16(x);
  return *reinterpret_cast<unsigned short*>(&h);
}
__device__ inline float tanh_fast(float v) {
  return 1.f - 2.f / (__expf(2.f * v) + 1.f);
}

// ---------------- K1: fused prep über-kernel (4 independent segments) ----------------
__global__ __launch_bounds__(256) void k_preps(const float* __restrict__ E,
                                               const float* __restrict__ c,
                                               const float* __restrict__ state,
                                               const float* __restrict__ Wp,
                                               unsigned short* __restrict__ A16,
                                               unsigned short* __restrict__ cT16,
                                               half_t* __restrict__ WpT,
                                               half_t* __restrict__ th16h,
                                               half_t* __restrict__ thq16h) {
  __shared__ float sbuf[4 * 2304];  // 36,864 B union
  const int id = blockIdx.x;
  const int t = threadIdx.x;
  if (id < 512) {
    // ---- seg A: rowsoftmax, 4 rows ----
    float(*row)[NN] = (float(*)[NN])sbuf;
    float(*red)[256] = (float(*)[256])(sbuf + 4 * NN);
    const int n = id * 4;
    float4 e[4][4];
#pragma unroll
    for (int r = 0; r < 4; ++r) {
      const float4* Er = (const float4*)(E + (size_t)(n + r) * ADA);
#pragma unroll
      for (int j = 0; j < 4; ++j) e[r][j] = Er[j];
    }
    float l[4] = {0.f, 0.f, 0.f, 0.f};
    for (int m = t; m < NN; m += 256) {
      const float4* Em = (const float4*)(E + (size_t)m * ADA);
      float4 ev[4];
#pragma unroll
      for (int j = 0; j < 4; ++j) ev[j] = Em[j];
#pragma unroll
      for (int r = 0; r < 4; ++r) {
        float s = 0.f;
#pragma unroll
        for (int j = 0; j < 4; ++j) {
          s = fmaf(e[r][j].x, ev[j].x, s);
          s = fmaf(e[r][j].y, ev[j].y, s);
          s = fmaf(e[r][j].z, ev[j].z, s);
          s = fmaf(e[r][j].w, ev[j].w, s);
        }
        float p = __expf(fmaxf(s, 0.f) - 20.f);  // fixed shift; cancels in normalize
        row[r][m] = p;
        l[r] += p;
      }
    }
#pragma unroll
    for (int r = 0; r < 4; ++r) red[r][t] = l[r];
    __syncthreads();
    for (int off = 128; off > 0; off >>= 1) {
      if (t < off) {
#pragma unroll
        for (int r = 0; r < 4; ++r) red[r][t] += red[r][t + off];
      }
      __syncthreads();
    }
    float inv[4];
#pragma unroll
    for (int r = 0; r < 4; ++r) inv[r] = 1.f / red[r][0];
    for (int m = t; m < NN; m += 256) {
#pragma unroll
      for (int r = 0; r < 4; ++r)
        A16[(size_t)(n + r) * NN + m] = f2bf(row[r][m] * inv[r]);
    }
  } else if (id < 768) {
    // ---- seg B: c transpose -> bf16 ----
    float(*ld)[68] = (float(*)[68])sbuf;
    const int idx = id - 512;
    const int m0 = (idx & 31) * 64;
    const int b = idx >> 5;
    {
      const int r = t & 63, cq = t >> 6;
      const float* cp = c + ((size_t)b * NN + m0 + r) * LL + cq * 16;
#pragma unroll
      for (int u = 0; u < 4; ++u)
        *(float4*)&ld[r][cq * 16 + 4 * u] = *(const float4*)(cp + 4 * u);
    }
    __syncthreads();
    const int o = t & 63, mq = t >> 6;
    unsigned short outv[16];
#pragma unroll
    for (int v = 0; v < 16; ++v) outv[v] = f2bf(ld[mq * 16 + v][o]);
    unsigned short* op = cT16 + ((size_t)b * LL + o) * NN + m0 + mq * 16;
    *(ushort8v*)op = *(const ushort8v*)&outv[0];
    *(ushort8v*)(op + 8) = *(const ushort8v*)&outv[8];
  } else if (id < 800) {
    // ---- seg C: Wp transpose -> fp16 ----
    float(*ld)[68] = (float(*)[68])sbuf;
    const int k0 = (id - 768) * 64;
    {
      const int r = t & 63, cq = t >> 6;
      const float* wp = Wp + (size_t)(k0 + r) * LL + cq * 16;
#pragma unroll
      for (int u = 0; u < 4; ++u)
        *(float4*)&ld[r][cq * 16 + 4 * u] = *(const float4*)(wp + 4 * u);
    }
    __syncthreads();
    const int o = t & 63, kq = t >> 6;
    halfx8 h0, h1;
#pragma unroll
    for (int v = 0; v < 8; ++v) {
      h0[v] = (half_t)ld[kq * 16 + v][o];
      h1[v] = (half_t)ld[kq * 16 + 8 + v][o];
    }
    half_t* op = WpT + (size_t)o * KT + k0 + kq * 16;
    *(halfx8*)op = h0;
    *(halfx8*)(op + 8) = h1;
  } else {
    // ---- seg D: th/thq from state (thread: row r, head h) ----
    const int idx = id - 800;
    const int n0 = (idx & 31) * 64;
    const int b = idx >> 5;
    const int r = t >> 2, h = t & 3;
    const float QS = 0.25f * 1.4426950408889634f;  // score scale + log2(e) into Q
    const float* sp = state + ((size_t)b * NN + n0 + r) * LL + h * DH;
    half_t tk[16], tq[16];
#pragma unroll
    for (int u = 0; u < 4; ++u) {
      float4 sv = *(const float4*)(sp + 4 * u);
      tk[4 * u + 0] = (half_t)sv.x; tk[4 * u + 1] = (half_t)sv.y;
      tk[4 * u + 2] = (half_t)sv.z; tk[4 * u + 3] = (half_t)sv.w;
      tq[4 * u + 0] = (half_t)(QS * sv.x); tq[4 * u + 1] = (half_t)(QS * sv.y);
      tq[4 * u + 2] = (half_t)(QS * sv.z); tq[4 * u + 3] = (half_t)(QS * sv.w);
    }
    const size_t base = ((size_t)(h * 8 + b) * NN + n0 + r) * DH;
    *(halfx8*)(th16h + base) = *(const halfx8*)&tk[0];
    *(halfx8*)(th16h + base + 8) = *(const halfx8*)&tk[8];
    *(halfx8*)(thq16h + base) = *(const halfx8*)&tq[0];
    *(halfx8*)(thq16h + base + 8) = *(const halfx8*)&tq[8];
  }
}

// ---------------- K2: fused cg-GEMM + GCN ----------------
// Phase 1 (gemm1 verbatim, full K): gacc = A@c tile (64 n x 64 o)
// Phase 2: fragment transpose via LDS -> xr[4..7]
// Phase 3 (gcn3 verbatim, all 16 d, bias on): tanh -> vt16h direct
__global__ __launch_bounds__(256) void k_gcnf(const unsigned short* __restrict__ A16,
                                              const unsigned short* __restrict__ cT16,
                                              const float* __restrict__ E,
                                              const half_t* __restrict__ WpT,
                                              const float* __restrict__ bp,
                                              const float* __restrict__ c,
                                              half_t* __restrict__ vt16h) {
  __shared__ __align__(16) char smemU[36864];  // union: sA+sB | cgs | sW
  __shared__ float sE[64][17];
  __shared__ float sbp[16][64];
  unsigned short(*sA)[72] = (unsigned short(*)[72])smemU;
  unsigned short(*sB)[72] = (unsigned short(*)[72])(smemU + 18432);
  float(*cgs)[68] = (float(*)[68])smemU;          // 17408 B
  half_t(*sW)[136] = (half_t(*)[136])smemU;       // 17408 B
  const int t = threadIdx.x;
  const int n0 = blockIdx.x * 64;
  const int b = blockIdx.y;
  const int wv = t >> 6, lane = t & 63;
  const int lr = lane & 15, lg = lane >> 4;
  {
    const int r = t >> 2, dq = (t & 3) * 4;
    float4 ev = *(const float4*)(E + (size_t)(n0 + r) * ADA + dq);
    sE[r][dq + 0] = ev.x; sE[r][dq + 1] = ev.y;
    sE[r][dq + 2] = ev.z; sE[r][dq + 3] = ev.w;
    const int bi = t * 4;
    *(float4*)&sbp[bi >> 6][bi & 63] = *(const float4*)(bp + bi);
  }
  // xr[0..3] from c (gcn3 verbatim)
  float xr[8][4];
  {
    const size_t rbase = ((size_t)b * NN + n0 + 16 * wv + lr) * LL;
#pragma unroll
    for (int q = 0; q < 4; ++q) {
      float4 v = *(const float4*)(c + rbase + q * 16 + 4 * lg);
      xr[q][0] = v.x; xr[q][1] = v.y; xr[q][2] = v.z; xr[q][3] = v.w;
    }
  }
  // ---- phase 1: cg tile = A @ c[b] (gemm1 inner loop, full K) ----
  const unsigned short* cb = cT16 + (size_t)b * LL * NN;
  const int sr = t >> 2, sc2 = (t & 3) * 16;
  f32x4 gacc[4];
#pragma unroll
  for (int ot = 0; ot < 4; ++ot) gacc[ot] = (f32x4){0.f, 0.f, 0.f, 0.f};
  for (int k0 = 0; k0 < NN; k0 += 64) {
    __syncthreads();
    {
      const unsigned short* ga = A16 + (size_t)(n0 + sr) * NN + k0 + sc2;
      *(ushort8v*)&sA[sr][sc2] = *(const ushort8v*)ga;
      *(ushort8v*)&sA[sr][sc2 + 8] = *(const ushort8v*)(ga + 8);
      const unsigned short* gb = cb + (size_t)sr * NN + k0 + sc2;
      *(ushort8v*)&sB[sr][sc2] = *(const ushort8v*)gb;
      *(ushort8v*)&sB[sr][sc2 + 8] = *(const ushort8v*)(gb + 8);
    }
    __syncthreads();
#pragma unroll
    for (int ks = 0; ks < 4; ++ks) {
      bf16x4 a = *(const bf16x4*)&sA[16 * wv + lr][ks * 16 + 4 * lg];
#pragma unroll
      for (int ot = 0; ot < 4; ++ot) {
        bf16x4 bq = *(const bf16x4*)&sB[ot * 16 + lr][ks * 16 + 4 * lg];
        gacc[ot] = MFMA16(a, bq, gacc[ot]);
      }
    }
  }
  // ---- phase 2: fragment transpose via cgs (aliases sA/sB region) ----
  __syncthreads();  // phase-1 MFMAs done reading sA/sB
#pragma unroll
  for (int ot = 0; ot < 4; ++ot)
#pragma unroll
    for (int reg = 0; reg < 4; ++reg)
      cgs[16 * wv + 4 * lg + reg][ot * 16 + lr] = gacc[ot][reg];
  __syncthreads();
#pragma unroll
  for (int q = 0; q < 4; ++q) {
    float4 v = *(const float4*)&cgs[16 * wv + lr][q * 16 + 4 * lg];
    xr[4 + q][0] = v.x; xr[4 + q][1] = v.y; xr[4 + q][2] = v.z; xr[4 + q][3] = v.w;
  }
  __syncthreads();  // cgs reads done before sW staging overwrites region
  // ---- phase 3: gcn (gcn3 verbatim, all d, bias always) ----
  f32x4 acc[4];
#pragma unroll
  for (int ot = 0; ot < 4; ++ot) {
    f32x4 s = (f32x4){0.f, 0.f, 0.f, 0.f};
#pragma unroll
    for (int d = 0; d < ADA; ++d) {
      const float bpv = sbp[d][ot * 16 + lr];
#pragma unroll
      for (int reg = 0; reg < 4; ++reg)
        s[reg] = fmaf(sE[16 * wv + 4 * lg + reg][d], bpv, s[reg]);
    }
    acc[ot] = s;
  }
  const int so = t >> 2, sq = t & 3;
  halfx8 wreg[4];
  {
    const half_t* p = WpT + (size_t)so * KT;
#pragma unroll
    for (int u = 0; u < 4; ++u) wreg[u] = *(const halfx8*)(p + (sq + 4 * u) * 8);
  }
  for (int dd = 0; dd < ADA; ++dd) {
    __syncthreads();  // previous iteration's MFMAs done with sW
#pragma unroll
    for (int u = 0; u < 4; ++u) *(halfx8*)&sW[so][(sq + 4 * u) * 8] = wreg[u];
    __syncthreads();  // sW ready
    if (dd < ADA - 1) {
      const half_t* p = WpT + (size_t)so * KT + (size_t)(dd + 1) * 128;
#pragma unroll
      for (int u = 0; u < 4; ++u) wreg[u] = *(const halfx8*)(p + (sq + 4 * u) * 8);
    }
    const float e = sE[16 * wv + lr][dd];
    halfx4 af[8];
#pragma unroll
    for (int kt = 0; kt < 8; ++kt)
#pragma unroll
      for (int j = 0; j < 4; ++j) af[kt][j] = (half_t)(e * xr[kt][j]);
#pragma unroll
    for (int kt = 0; kt < 8; ++kt) {
#pragma unroll
      for (int ot = 0; ot < 4; ++ot) {
        halfx4 bq = *(const halfx4*)&sW[ot * 16 + lr][kt * 16 + 4 * lg];
        acc[ot] = MFMA16H(af[kt], bq, acc[ot]);
      }
    }
  }
  // epilogue (R14-validated, h = ot): tanh + direct transposed fp16 store
#pragma unroll
  for (int ot = 0; ot < 4; ++ot) {
    halfx4 o4;
#pragma unroll
    for (int reg = 0; reg < 4; ++reg) o4[reg] = (half_t)tanh_fast(acc[ot][reg]);
    *(halfx4*)(vt16h + ((size_t)(ot * 8 + b) * DH + lr) * NN + n0 + 16 * wv + 4 * lg) = o4;
  }
}

// ---------------- K3: fp16 MFMA attention — 128 q/block (8 frags/wave), m split 8-way ----------------
__global__ __launch_bounds__(512, 4) void k_attn5(const half_t* __restrict__ th16h,
                                                  const half_t* __restrict__ thq16h,
                                                  const half_t* __restrict__ vt16h,
                                                  float* __restrict__ out) {
  __shared__ float sred[8][8][16][16];  // 64 KB: phase A den (first 4 KB), phase B num
  float* dfl = &sred[0][0][0][0];
  const int hb = blockIdx.x;
  const int h = hb >> 3, b = hb & 7;
  const int wv = threadIdx.x >> 6, lane = threadIdx.x & 63;
  const int q0 = blockIdx.y * 128;
  const int lr = lane & 15, lg = lane >> 4;
  const half_t* th = th16h + (size_t)hb * NN * DH;
  const half_t* thq = thq16h + (size_t)hb * NN * DH;
  const half_t* vrow = vt16h + ((size_t)hb * DH + lr) * NN;  // V^T row d=lr
  halfx4 qf[8];
#pragma unroll
  for (int f = 0; f < 8; ++f)
    qf[f] = *(const halfx4*)(thq + (size_t)(q0 + 16 * f + lr) * DH + 4 * lg);
  // shift-8 softmax via MFMA C-init (fp16-safe, cancels in num/den)
  const float SH = 8.f * 1.4426950408889634f;
  const f32x4 shiftv = {-SH, -SH, -SH, -SH};
  f32x4 acc[8];
  float den[8];
#pragma unroll
  for (int f = 0; f < 8; ++f) { acc[f] = (f32x4){0.f, 0.f, 0.f, 0.f}; den[f] = 0.f; }

  const int mb = wv * (NN / 8);  // this wave's 256-row m-slice
  halfx4 kf = *(const halfx4*)(th + (size_t)(mb + lr) * DH + 4 * lg);
  halfx4 vf = *(const halfx4*)(vrow + mb + 4 * lg);
  for (int mt = 0; mt < NN / 128; ++mt) {  // 16 tiles of 16
    halfx4 kf_n = kf, vf_n = vf;
    if (mt < NN / 128 - 1) {
      const int mn = mb + (mt + 1) * 16;
      kf_n = *(const halfx4*)(th + (size_t)(mn + lr) * DH + 4 * lg);
      vf_n = *(const halfx4*)(vrow + mn + 4 * lg);
    }
#pragma unroll
    for (int f = 0; f < 8; ++f) {
      f32x4 s = MFMA16H(kf, qf[f], shiftv);  // lane: col q, rows m; pre-shifted
      float p0 = EXP2F(s[0]), p1 = EXP2F(s[1]), p2 = EXP2F(s[2]), p3 = EXP2F(s[3]);
      den[f] += (p0 + p1) + (p2 + p3);
      halfx2 lo = cvt_pk2(p0, p1), hi = cvt_pk2(p2, p3);
      halfx4 pf;
      pf[0] = lo[0]; pf[1] = lo[1]; pf[2] = hi[0]; pf[3] = hi[1];
      acc[f] = MFMA16H(pf, vf, acc[f]);  // lane: col d=lr, rows q=16f+4lg+reg
    }
    kf = kf_n; vf = vf_n;
  }
#pragma unroll
  for (int f = 0; f < 8; ++f) {
    den[f] += __shfl_xor(den[f], 16);
    den[f] += __shfl_xor(den[f], 32);
  }
  // phase A: den partials (8 waves x 8 frags x 16 q = 4 KB of sred)
  if (lane < 16) {
#pragma unroll
    for (int f = 0; f < 8; ++f) dfl[(wv * 8 + f) * 16 + lane] = den[f];
  }
  __syncthreads();
  const int t = threadIdx.x;
  const int fo = t >> 6, ro = (t >> 2) & 15, duo = (t & 3) * 4;
  float ds = 0.f;
#pragma unroll
  for (int w = 0; w < 8; ++w) ds += dfl[(w * 8 + fo) * 16 + ro];
  __syncthreads();  // done reading den region before overwrite
  // phase B: numerator partials
#pragma unroll
  for (int f = 0; f < 8; ++f) {
#pragma unroll
    for (int reg = 0; reg < 4; ++reg) sred[wv][f][4 * lg + reg][lr] = acc[f][reg];
  }
  __syncthreads();
  float4 ns = make_float4(0.f, 0.f, 0.f, 0.f);
#pragma unroll
  for (int w = 0; w < 8; ++w) {
    float4 v = *(const float4*)&sred[w][fo][ro][duo];
    ns.x += v.x; ns.y += v.y; ns.z += v.z; ns.w += v.w;
  }
  const float inv = -1.f / ds;
  float4 o = make_float4(ns.x * inv, ns.y * inv, ns.z * inv, ns.w * inv);
  *(float4*)(out + ((size_t)b * NN + q0 + 16 * fo + ro) * LL + h * DH + duo) = o;
}

extern "C" void kernel_launch(void* const* d_in, const int* in_sizes, int n_in,
                              void* d_out, int out_size, void* d_ws, size_t ws_size,
                              hipStream_t stream) {
  const float* c = (const float*)d_in[0];
  const float* state = (const float*)d_in[3];
  const float* E = (const float*)d_in[4];
  const float* Wp = (const float*)d_in[13];
  const float* bp = (const float*)d_in[14];
  float* out = (float*)d_out;

  unsigned short* A16 = (unsigned short*)d_ws;        // 2048*2048 bf16 = 8 MB
  unsigned short* cT16 = A16 + (size_t)NN * NN;       // 2 MB
  half_t* WpT = (half_t*)(cT16 + (size_t)BB * LL * NN);  // 256 KB
  half_t* th16h = WpT + (size_t)LL * KT;              // 2 MB
  half_t* thq16h = th16h + (size_t)HB * NN * DH;      // 2 MB
  half_t* vt16h = thq16h + (size_t)HB * NN * DH;      // 2 MB

  k_preps<<<1056, 256, 0, stream>>>(E, c, state, Wp, A16, cT16, WpT, th16h, thq16h);
  k_gcnf<<<dim3(NN / 64, BB), 256, 0, stream>>>(A16, cT16, E, WpT, bp, c, vt16h);
  k_attn5<<<dim3(HB, NN / 128), 512, 0, stream>>>(th16h, thq16h, vt16h, out);
}

// Round 16
// 73.678 us; speedup vs baseline: 1.1569x; 1.1569x over previous
//
#include <hip/hip_runtime.h>
#include <hip/hip_bf16.h>

#define NN 2048
#define BB 8
#define LL 64
#define ADA 16
#define DH 16
#define HB 32
#define KT 2048   // GCN GEMM total K = ADA*2*LL
#define CGSZ ((size_t)BB * NN * LL)  // one cg partial buffer

typedef __attribute__((ext_vector_type(4))) short bf16x4;
typedef __attribute__((ext_vector_type(4))) float f32x4;
typedef __attribute__((ext_vector_type(8))) unsigned short ushort8v;
typedef _Float16 half_t;
typedef __attribute__((ext_vector_type(2))) _Float16 halfx2;
typedef __attribute__((ext_vector_type(4))) _Float16 halfx4;
typedef __attribute__((ext_vector_type(8))) _Float16 halfx8;

// __has_builtin(__builtin_amdgcn_mfma_*) is FALSE on the host pass of hipcc's
// dual compile -> guard with __HIP_DEVICE_COMPILE__, parse-only dummy on host.
#if defined(__HIP_DEVICE_COMPILE__)
#if __has_builtin(__builtin_amdgcn_mfma_f32_16x16x16bf16_1k)
#define MFMA16(a, b, c) __builtin_amdgcn_mfma_f32_16x16x16bf16_1k(a, b, c, 0, 0, 0)
#elif __has_builtin(__builtin_amdgcn_mfma_f32_16x16x16_bf16)
#define MFMA16(a, b, c) __builtin_amdgcn_mfma_f32_16x16x16_bf16(a, b, c, 0, 0, 0)
#else
#error "no 16x16x16 bf16 mfma builtin on device"
#endif
#if __has_builtin(__builtin_amdgcn_mfma_f32_16x16x16f16)
#define MFMA16H(a, b, c) __builtin_amdgcn_mfma_f32_16x16x16f16(a, b, c, 0, 0, 0)
#elif __has_builtin(__builtin_amdgcn_mfma_f32_16x16x16_f16)
#define MFMA16H(a, b, c) __builtin_amdgcn_mfma_f32_16x16x16_f16(a, b, c, 0, 0, 0)
#else
#error "no 16x16x16 f16 mfma builtin on device"
#endif
#if __has_builtin(__builtin_amdgcn_exp2f)
#define EXP2F(x) __builtin_amdgcn_exp2f(x)
#else
#define EXP2F(x) exp2f(x)
#endif
#else
#define MFMA16(a, b, c) (c)
#define MFMA16H(a, b, c) (c)
#define EXP2F(x) exp2f(x)
#endif

__device__ inline halfx2 cvt_pk2(float a, float b) {
#if defined(__HIP_DEVICE_COMPILE__) && __has_builtin(__builtin_amdgcn_cvt_pkrtz)
  auto r = __builtin_amdgcn_cvt_pkrtz(a, b);
  return __builtin_bit_cast(halfx2, r);
#else
  halfx2 r;
  r[0] = (_Float16)a;
  r[1] = (_Float16)b;
  return r;
#endif
}

__device__ inline unsigned short f2bf(float x) {
  __hip_bfloat16 h = __float2bfloat16(x);
  return *reinterpret_cast<unsigned short*>(&h);
}
__device__ inline float tanh_fast(float v) {
  return 1.f - 2.f / (__expf(2.f * v) + 1.f);
}

// ---------------- K1: fused prep über-kernel (4 independent segments) ----------------
__global__ __launch_bounds__(256) void k_preps(const float* __restrict__ E,
                                               const float* __restrict__ c,
                                               const float* __restrict__ state,
                                               const float* __restrict__ Wp,
                                               unsigned short* __restrict__ A16,
                                               unsigned short* __restrict__ cT16,
                                               half_t* __restrict__ WpT,
                                               half_t* __restrict__ th16h,
                                               half_t* __restrict__ thq16h) {
  __shared__ float sbuf[4 * 2304];  // 36,864 B union
  const int id = blockIdx.x;
  const int t = threadIdx.x;
  if (id < 512) {
    // ---- seg A: rowsoftmax, 4 rows ----
    float(*row)[NN] = (float(*)[NN])sbuf;
    float(*red)[256] = (float(*)[256])(sbuf + 4 * NN);
    const int n = id * 4;
    float4 e[4][4];
#pragma unroll
    for (int r = 0; r < 4; ++r) {
      const float4* Er = (const float4*)(E + (size_t)(n + r) * ADA);
#pragma unroll
      for (int j = 0; j < 4; ++j) e[r][j] = Er[j];
    }
    float l[4] = {0.f, 0.f, 0.f, 0.f};
    for (int m = t; m < NN; m += 256) {
      const float4* Em = (const float4*)(E + (size_t)m * ADA);
      float4 ev[4];
#pragma unroll
      for (int j = 0; j < 4; ++j) ev[j] = Em[j];
#pragma unroll
      for (int r = 0; r < 4; ++r) {
        float s = 0.f;
#pragma unroll
        for (int j = 0; j < 4; ++j) {
          s = fmaf(e[r][j].x, ev[j].x, s);
          s = fmaf(e[r][j].y, ev[j].y, s);
          s = fmaf(e[r][j].z, ev[j].z, s);
          s = fmaf(e[r][j].w, ev[j].w, s);
        }
        float p = __expf(fmaxf(s, 0.f) - 20.f);  // fixed shift; cancels in normalize
        row[r][m] = p;
        l[r] += p;
      }
    }
#pragma unroll
    for (int r = 0; r < 4; ++r) red[r][t] = l[r];
    __syncthreads();
    for (int off = 128; off > 0; off >>= 1) {
      if (t < off) {
#pragma unroll
        for (int r = 0; r < 4; ++r) red[r][t] += red[r][t + off];
      }
      __syncthreads();
    }
    float inv[4];
#pragma unroll
    for (int r = 0; r < 4; ++r) inv[r] = 1.f / red[r][0];
    for (int m = t; m < NN; m += 256) {
#pragma unroll
      for (int r = 0; r < 4; ++r)
        A16[(size_t)(n + r) * NN + m] = f2bf(row[r][m] * inv[r]);
    }
  } else if (id < 768) {
    // ---- seg B: c transpose -> bf16 ----
    float(*ld)[68] = (float(*)[68])sbuf;
    const int idx = id - 512;
    const int m0 = (idx & 31) * 64;
    const int b = idx >> 5;
    {
      const int r = t & 63, cq = t >> 6;
      const float* cp = c + ((size_t)b * NN + m0 + r) * LL + cq * 16;
#pragma unroll
      for (int u = 0; u < 4; ++u)
        *(float4*)&ld[r][cq * 16 + 4 * u] = *(const float4*)(cp + 4 * u);
    }
    __syncthreads();
    const int o = t & 63, mq = t >> 6;
    unsigned short outv[16];
#pragma unroll
    for (int v = 0; v < 16; ++v) outv[v] = f2bf(ld[mq * 16 + v][o]);
    unsigned short* op = cT16 + ((size_t)b * LL + o) * NN + m0 + mq * 16;
    *(ushort8v*)op = *(const ushort8v*)&outv[0];
    *(ushort8v*)(op + 8) = *(const ushort8v*)&outv[8];
  } else if (id < 800) {
    // ---- seg C: Wp transpose -> fp16 ----
    float(*ld)[68] = (float(*)[68])sbuf;
    const int k0 = (id - 768) * 64;
    {
      const int r = t & 63, cq = t >> 6;
      const float* wp = Wp + (size_t)(k0 + r) * LL + cq * 16;
#pragma unroll
      for (int u = 0; u < 4; ++u)
        *(float4*)&ld[r][cq * 16 + 4 * u] = *(const float4*)(wp + 4 * u);
    }
    __syncthreads();
    const int o = t & 63, kq = t >> 6;
    halfx8 h0, h1;
#pragma unroll
    for (int v = 0; v < 8; ++v) {
      h0[v] = (half_t)ld[kq * 16 + v][o];
      h1[v] = (half_t)ld[kq * 16 + 8 + v][o];
    }
    half_t* op = WpT + (size_t)o * KT + k0 + kq * 16;
    *(halfx8*)op = h0;
    *(halfx8*)(op + 8) = h1;
  } else {
    // ---- seg D: th/thq from state (thread: row r, head h) ----
    const int idx = id - 800;
    const int n0 = (idx & 31) * 64;
    const int b = idx >> 5;
    const int r = t >> 2, h = t & 3;
    const float QS = 0.25f * 1.4426950408889634f;  // score scale + log2(e) into Q
    const float* sp = state + ((size_t)b * NN + n0 + r) * LL + h * DH;
    half_t tk[16], tq[16];
#pragma unroll
    for (int u = 0; u < 4; ++u) {
      float4 sv = *(const float4*)(sp + 4 * u);
      tk[4 * u + 0] = (half_t)sv.x; tk[4 * u + 1] = (half_t)sv.y;
      tk[4 * u + 2] = (half_t)sv.z; tk[4 * u + 3] = (half_t)sv.w;
      tq[4 * u + 0] = (half_t)(QS * sv.x); tq[4 * u + 1] = (half_t)(QS * sv.y);
      tq[4 * u + 2] = (half_t)(QS * sv.z); tq[4 * u + 3] = (half_t)(QS * sv.w);
    }
    const size_t base = ((size_t)(h * 8 + b) * NN + n0 + r) * DH;
    *(halfx8*)(th16h + base) = *(const halfx8*)&tk[0];
    *(halfx8*)(th16h + base + 8) = *(const halfx8*)&tk[8];
    *(halfx8*)(thq16h + base) = *(const halfx8*)&tq[0];
    *(halfx8*)(thq16h + base + 8) = *(const halfx8*)&tq[8];
  }
}

// ---------------- K2: cg[b] = A @ c[b], bf16 16x16x16 MFMA, K-split x4 ----------------
__global__ __launch_bounds__(256) void k_gemm1(const unsigned short* __restrict__ A16,
                                               const unsigned short* __restrict__ cT16,
                                               float* __restrict__ cg) {
  __shared__ unsigned short sA[64][72];
  __shared__ unsigned short sB[64][72];
  const int t = threadIdx.x;
  const int n0 = blockIdx.x * 64;
  const int b = blockIdx.y;
  const int kh = blockIdx.z;  // 0..3
  const int wv = t >> 6, lane = t & 63;
  const int lr = lane & 15, lg = lane >> 4;
  const unsigned short* cb = cT16 + (size_t)b * LL * NN;
  const int sr = t >> 2, sc = (t & 3) * 16;
  f32x4 acc[4];
#pragma unroll
  for (int ot = 0; ot < 4; ++ot) acc[ot] = (f32x4){0.f, 0.f, 0.f, 0.f};

  for (int k0 = kh * (NN / 4); k0 < (kh + 1) * (NN / 4); k0 += 64) {  // 8 k-tiles
    __syncthreads();
    {
      const unsigned short* ga = A16 + (size_t)(n0 + sr) * NN + k0 + sc;
      *(ushort8v*)&sA[sr][sc] = *(const ushort8v*)ga;
      *(ushort8v*)&sA[sr][sc + 8] = *(const ushort8v*)(ga + 8);
      const unsigned short* gb = cb + (size_t)sr * NN + k0 + sc;
      *(ushort8v*)&sB[sr][sc] = *(const ushort8v*)gb;
      *(ushort8v*)&sB[sr][sc + 8] = *(const ushort8v*)(gb + 8);
    }
    __syncthreads();
#pragma unroll
    for (int ks = 0; ks < 4; ++ks) {
      bf16x4 a = *(const bf16x4*)&sA[16 * wv + lr][ks * 16 + 4 * lg];
#pragma unroll
      for (int ot = 0; ot < 4; ++ot) {
        bf16x4 bq = *(const bf16x4*)&sB[ot * 16 + lr][ks * 16 + 4 * lg];
        acc[ot] = MFMA16(a, bq, acc[ot]);
      }
    }
  }
  float* outp = cg + (size_t)kh * CGSZ + ((size_t)b * NN + n0 + 16 * wv) * LL;
#pragma unroll
  for (int ot = 0; ot < 4; ++ot)
#pragma unroll
    for (int reg = 0; reg < 4; ++reg)
      outp[(size_t)(4 * lg + reg) * LL + ot * 16 + lr] = acc[ot][reg];
}

// ---------------- K3: gcn4 — ct = tanh(sum_d E*(xg@Wp[d]) + E@bp), o-split x2, fused vt write ----------------
__global__ __launch_bounds__(256) void k_gcn4(const float* __restrict__ E,
                                              const half_t* __restrict__ WpT,
                                              const float* __restrict__ bp,
                                              const float* __restrict__ c,
                                              const float* __restrict__ cg,
                                              half_t* __restrict__ vt16h) {
  __shared__ half_t sW[32][136];  // 32 o-rows x 128 k (per d) + pad, 8.7 KB
  __shared__ float sE[64][17];
  __shared__ float sbp[16][32];
  const int t = threadIdx.x;
  const int n0 = blockIdx.x * 64;
  const int b = blockIdx.y;
  const int oh = blockIdx.z;  // o in [oh*32, oh*32+32)
  const int wv = t >> 6, lane = t & 63;
  const int lr = lane & 15, lg = lane >> 4;
  {
    const int r = t >> 2, dq = (t & 3) * 4;
    float4 ev = *(const float4*)(E + (size_t)(n0 + r) * ADA + dq);
    sE[r][dq + 0] = ev.x; sE[r][dq + 1] = ev.y;
    sE[r][dq + 2] = ev.z; sE[r][dq + 3] = ev.w;
    const int d = t >> 4, o2 = (t & 15) * 2;  // bias slice [16][32]
    float2 bv = *(const float2*)(bp + d * LL + oh * 32 + o2);
    sbp[d][o2] = bv.x;
    sbp[d][o2 + 1] = bv.y;
  }
  // x (c | sum of 4 cg partials) into registers. A-frag row = lr, k = 4*lg+j per 16-k tile.
  float xr[8][4];
  {
    const size_t rbase = ((size_t)b * NN + n0 + 16 * wv + lr) * LL;
#pragma unroll
    for (int q = 0; q < 4; ++q) {
      float4 v = *(const float4*)(c + rbase + q * 16 + 4 * lg);
      xr[q][0] = v.x; xr[q][1] = v.y; xr[q][2] = v.z; xr[q][3] = v.w;
    }
#pragma unroll
    for (int q = 0; q < 4; ++q) {
      float4 s0 = *(const float4*)(cg + rbase + q * 16 + 4 * lg);
      float4 s1 = *(const float4*)(cg + CGSZ + rbase + q * 16 + 4 * lg);
      float4 s2 = *(const float4*)(cg + 2 * CGSZ + rbase + q * 16 + 4 * lg);
      float4 s3 = *(const float4*)(cg + 3 * CGSZ + rbase + q * 16 + 4 * lg);
      xr[4 + q][0] = (s0.x + s1.x) + (s2.x + s3.x);
      xr[4 + q][1] = (s0.y + s1.y) + (s2.y + s3.y);
      xr[4 + q][2] = (s0.z + s1.z) + (s2.z + s3.z);
      xr[4 + q][3] = (s0.w + s1.w) + (s2.w + s3.w);
    }
  }
  __syncthreads();
  // acc init with bias; D rows = 16wv+4lg+reg (n), cols = ot2*16+lr (o local)
  f32x4 acc[2];
#pragma unroll
  for (int ot2 = 0; ot2 < 2; ++ot2) {
    f32x4 s = (f32x4){0.f, 0.f, 0.f, 0.f};
#pragma unroll
    for (int d = 0; d < ADA; ++d) {
      const float bpv = sbp[d][ot2 * 16 + lr];
#pragma unroll
      for (int reg = 0; reg < 4; ++reg)
        s[reg] = fmaf(sE[16 * wv + 4 * lg + reg][d], bpv, s[reg]);
    }
    acc[ot2] = s;
  }
  // W staging: thread covers o-row so (0..31), 16-half chunk sq (0..7)
  const int so = t >> 3, sq = t & 7;
  halfx8 wreg[2];
  {
    const half_t* p = WpT + (size_t)(oh * 32 + so) * KT + sq * 16;
    wreg[0] = *(const halfx8*)p;
    wreg[1] = *(const halfx8*)(p + 8);
  }
  for (int dd = 0; dd < ADA; ++dd) {
    __syncthreads();  // previous iteration's MFMAs done with sW
    *(halfx8*)&sW[so][sq * 16] = wreg[0];
    *(halfx8*)&sW[so][sq * 16 + 8] = wreg[1];
    __syncthreads();  // sW ready
    if (dd < ADA - 1) {
      const half_t* p = WpT + (size_t)(oh * 32 + so) * KT + (dd + 1) * 128 + sq * 16;
      wreg[0] = *(const halfx8*)p;
      wreg[1] = *(const halfx8*)(p + 8);
    }
    const float e = sE[16 * wv + lr][dd];
    halfx4 af[8];
#pragma unroll
    for (int kt = 0; kt < 8; ++kt)
#pragma unroll
      for (int j = 0; j < 4; ++j) af[kt][j] = (half_t)(e * xr[kt][j]);
#pragma unroll
    for (int kt = 0; kt < 8; ++kt) {
#pragma unroll
      for (int ot2 = 0; ot2 < 2; ++ot2) {
        halfx4 bq = *(const halfx4*)&sW[ot2 * 16 + lr][kt * 16 + 4 * lg];
        acc[ot2] = MFMA16H(af[kt], bq, acc[ot2]);
      }
    }
  }
  // epilogue: tanh + direct transposed fp16 store to vt16h[hb][d=lr][n]
#pragma unroll
  for (int ot2 = 0; ot2 < 2; ++ot2) {
    const int h = oh * 2 + ot2;
    halfx4 o4;
#pragma unroll
    for (int reg = 0; reg < 4; ++reg) o4[reg] = (half_t)tanh_fast(acc[ot2][reg]);
    *(halfx4*)(vt16h + ((size_t)(h * 8 + b) * DH + lr) * NN + n0 + 16 * wv + 4 * lg) = o4;
  }
}

// ---------------- K4: fp16 MFMA attention — 128 q/block (8 frags/wave), m split 8-way ----------------
__global__ __launch_bounds__(512, 4) void k_attn5(const half_t* __restrict__ th16h,
                                                  const half_t* __restrict__ thq16h,
                                                  const half_t* __restrict__ vt16h,
                                                  float* __restrict__ out) {
  __shared__ float sred[8][8][16][16];  // 64 KB: phase A den (first 4 KB), phase B num
  float* dfl = &sred[0][0][0][0];
  const int hb = blockIdx.x;
  const int h = hb >> 3, b = hb & 7;
  const int wv = threadIdx.x >> 6, lane = threadIdx.x & 63;
  const int q0 = blockIdx.y * 128;
  const int lr = lane & 15, lg = lane >> 4;
  const half_t* th = th16h + (size_t)hb * NN * DH;
  const half_t* thq = thq16h + (size_t)hb * NN * DH;
  const half_t* vrow = vt16h + ((size_t)hb * DH + lr) * NN;  // V^T row d=lr
  halfx4 qf[8];
#pragma unroll
  for (int f = 0; f < 8; ++f)
    qf[f] = *(const halfx4*)(thq + (size_t)(q0 + 16 * f + lr) * DH + 4 * lg);
  // shift-8 softmax via MFMA C-init (fp16-safe, cancels in num/den)
  const float SH = 8.f * 1.4426950408889634f;
  const f32x4 shiftv = {-SH, -SH, -SH, -SH};
  f32x4 acc[8];
  float den[8];
#pragma unroll
  for (int f = 0; f < 8; ++f) { acc[f] = (f32x4){0.f, 0.f, 0.f, 0.f}; den[f] = 0.f; }

  const int mb = wv * (NN / 8);  // this wave's 256-row m-slice
  halfx4 kf = *(const halfx4*)(th + (size_t)(mb + lr) * DH + 4 * lg);
  halfx4 vf = *(const halfx4*)(vrow + mb + 4 * lg);
  for (int mt = 0; mt < NN / 128; ++mt) {  // 16 tiles of 16
    halfx4 kf_n = kf, vf_n = vf;
    if (mt < NN / 128 - 1) {
      const int mn = mb + (mt + 1) * 16;
      kf_n = *(const halfx4*)(th + (size_t)(mn + lr) * DH + 4 * lg);
      vf_n = *(const halfx4*)(vrow + mn + 4 * lg);
    }
#pragma unroll
    for (int f = 0; f < 8; ++f) {
      f32x4 s = MFMA16H(kf, qf[f], shiftv);  // lane: col q, rows m; pre-shifted
      float p0 = EXP2F(s[0]), p1 = EXP2F(s[1]), p2 = EXP2F(s[2]), p3 = EXP2F(s[3]);
      den[f] += (p0 + p1) + (p2 + p3);
      halfx2 lo = cvt_pk2(p0, p1), hi = cvt_pk2(p2, p3);
      halfx4 pf;
      pf[0] = lo[0]; pf[1] = lo[1]; pf[2] = hi[0]; pf[3] = hi[1];
      acc[f] = MFMA16H(pf, vf, acc[f]);  // lane: col d=lr, rows q=16f+4lg+reg
    }
    kf = kf_n; vf = vf_n;
  }
#pragma unroll
  for (int f = 0; f < 8; ++f) {
    den[f] += __shfl_xor(den[f], 16);
    den[f] += __shfl_xor(den[f], 32);
  }
  // phase A: den partials (8 waves x 8 frags x 16 q = 4 KB of sred)
  if (lane < 16) {
#pragma unroll
    for (int f = 0; f < 8; ++f) dfl[(wv * 8 + f) * 16 + lane] = den[f];
  }
  __syncthreads();
  const int t = threadIdx.x;
  const int fo = t >> 6, ro = (t >> 2) & 15, duo = (t & 3) * 4;
  float ds = 0.f;
#pragma unroll
  for (int w = 0; w < 8; ++w) ds += dfl[(w * 8 + fo) * 16 + ro];
  __syncthreads();  // done reading den region before overwrite
  // phase B: numerator partials
#pragma unroll
  for (int f = 0; f < 8; ++f) {
#pragma unroll
    for (int reg = 0; reg < 4; ++reg) sred[wv][f][4 * lg + reg][lr] = acc[f][reg];
  }
  __syncthreads();
  float4 ns = make_float4(0.f, 0.f, 0.f, 0.f);
#pragma unroll
  for (int w = 0; w < 8; ++w) {
    float4 v = *(const float4*)&sred[w][fo][ro][duo];
    ns.x += v.x; ns.y += v.y; ns.z += v.z; ns.w += v.w;
  }
  const float inv = -1.f / ds;
  float4 o = make_float4(ns.x * inv, ns.y * inv, ns.z * inv, ns.w * inv);
  *(float4*)(out + ((size_t)b * NN + q0 + 16 * fo + ro) * LL + h * DH + duo) = o;
}

extern "C" void kernel_launch(void* const* d_in, const int* in_sizes, int n_in,
                              void* d_out, int out_size, void* d_ws, size_t ws_size,
                              hipStream_t stream) {
  const float* c = (const float*)d_in[0];
  const float* state = (const float*)d_in[3];
  const float* E = (const float*)d_in[4];
  const float* Wp = (const float*)d_in[13];
  const float* bp = (const float*)d_in[14];
  float* out = (float*)d_out;

  unsigned short* A16 = (unsigned short*)d_ws;        // 2048*2048 bf16 = 8 MB
  unsigned short* cT16 = A16 + (size_t)NN * NN;       // 2 MB
  half_t* WpT = (half_t*)(cT16 + (size_t)BB * LL * NN);  // 256 KB
  float* cg = (float*)(WpT + (size_t)LL * KT);        // 4 x 4 MB partials
  half_t* th16h = (half_t*)(cg + 4 * CGSZ);           // 2 MB
  half_t* thq16h = th16h + (size_t)HB * NN * DH;      // 2 MB
  half_t* vt16h = thq16h + (size_t)HB * NN * DH;      // 2 MB

  k_preps<<<1056, 256, 0, stream>>>(E, c, state, Wp, A16, cT16, WpT, th16h, thq16h);
  k_gemm1<<<dim3(NN / 64, BB, 4), 256, 0, stream>>>(A16, cT16, cg);
  k_gcn4<<<dim3(NN / 64, BB, 2), 256, 0, stream>>>(E, WpT, bp, c, cg, vt16h);
  k_attn5<<<dim3(HB, NN / 128), 512, 0, stream>>>(th16h, thq16h, vt16h, out);
}

// Round 17
// 73.581 us; speedup vs baseline: 1.1584x; 1.0013x over previous
//
#include <hip/hip_runtime.h>
#include <hip/hip_bf16.h>

#define NN 2048
#define BB 8
#define LL 64
#define ADA 16
#define DH 16
#define HB 32
#define KT 2048   // GCN GEMM total K = ADA*2*LL
#define CGSZ ((size_t)BB * NN * LL)  // one cg partial buffer

typedef __attribute__((ext_vector_type(4))) short bf16x4;
typedef __attribute__((ext_vector_type(4))) float f32x4;
typedef __attribute__((ext_vector_type(8))) unsigned short ushort8v;
typedef _Float16 half_t;
typedef __attribute__((ext_vector_type(2))) _Float16 halfx2;
typedef __attribute__((ext_vector_type(4))) _Float16 halfx4;
typedef __attribute__((ext_vector_type(8))) _Float16 halfx8;

// __has_builtin(__builtin_amdgcn_mfma_*) is FALSE on the host pass of hipcc's
// dual compile -> guard with __HIP_DEVICE_COMPILE__, parse-only dummy on host.
#if defined(__HIP_DEVICE_COMPILE__)
#if __has_builtin(__builtin_amdgcn_mfma_f32_16x16x16bf16_1k)
#define MFMA16(a, b, c) __builtin_amdgcn_mfma_f32_16x16x16bf16_1k(a, b, c, 0, 0, 0)
#elif __has_builtin(__builtin_amdgcn_mfma_f32_16x16x16_bf16)
#define MFMA16(a, b, c) __builtin_amdgcn_mfma_f32_16x16x16_bf16(a, b, c, 0, 0, 0)
#else
#error "no 16x16x16 bf16 mfma builtin on device"
#endif
#if __has_builtin(__builtin_amdgcn_mfma_f32_16x16x16f16)
#define MFMA16H(a, b, c) __builtin_amdgcn_mfma_f32_16x16x16f16(a, b, c, 0, 0, 0)
#elif __has_builtin(__builtin_amdgcn_mfma_f32_16x16x16_f16)
#define MFMA16H(a, b, c) __builtin_amdgcn_mfma_f32_16x16x16_f16(a, b, c, 0, 0, 0)
#else
#error "no 16x16x16 f16 mfma builtin on device"
#endif
#if __has_builtin(__builtin_amdgcn_exp2f)
#define EXP2F(x) __builtin_amdgcn_exp2f(x)
#else
#define EXP2F(x) exp2f(x)
#endif
#else
#define MFMA16(a, b, c) (c)
#define MFMA16H(a, b, c) (c)
#define EXP2F(x) exp2f(x)
#endif

__device__ inline halfx2 cvt_pk2(float a, float b) {
#if defined(__HIP_DEVICE_COMPILE__) && __has_builtin(__builtin_amdgcn_cvt_pkrtz)
  auto r = __builtin_amdgcn_cvt_pkrtz(a, b);
  return __builtin_bit_cast(halfx2, r);
#else
  halfx2 r;
  r[0] = (_Float16)a;
  r[1] = (_Float16)b;
  return r;
#endif
}

__device__ inline unsigned short f2bf(float x) {
  __hip_bfloat16 h = __float2bfloat16(x);
  return *reinterpret_cast<unsigned short*>(&h);
}
__device__ inline float tanh_fast(float v) {
  return 1.f - 2.f / (__expf(2.f * v) + 1.f);
}

// ---------------- K1: fused prep über-kernel (4 independent segments) ----------------
__global__ __launch_bounds__(256) void k_preps(const float* __restrict__ E,
                                               const float* __restrict__ c,
                                               const float* __restrict__ state,
                                               const float* __restrict__ Wp,
                                               unsigned short* __restrict__ A16,
                                               unsigned short* __restrict__ cT16,
                                               half_t* __restrict__ WpT,
                                               half_t* __restrict__ th16h,
                                               half_t* __restrict__ thq16h) {
  __shared__ float sbuf[4 * 2304];  // 36,864 B union
  const int id = blockIdx.x;
  const int t = threadIdx.x;
  if (id < 512) {
    // ---- seg A: rowsoftmax, 4 rows ----
    float(*row)[NN] = (float(*)[NN])sbuf;
    float(*red)[256] = (float(*)[256])(sbuf + 4 * NN);
    const int n = id * 4;
    float4 e[4][4];
#pragma unroll
    for (int r = 0; r < 4; ++r) {
      const float4* Er = (const float4*)(E + (size_t)(n + r) * ADA);
#pragma unroll
      for (int j = 0; j < 4; ++j) e[r][j] = Er[j];
    }
    float l[4] = {0.f, 0.f, 0.f, 0.f};
    for (int m = t; m < NN; m += 256) {
      const float4* Em = (const float4*)(E + (size_t)m * ADA);
      float4 ev[4];
#pragma unroll
      for (int j = 0; j < 4; ++j) ev[j] = Em[j];
#pragma unroll
      for (int r = 0; r < 4; ++r) {
        float s = 0.f;
#pragma unroll
        for (int j = 0; j < 4; ++j) {
          s = fmaf(e[r][j].x, ev[j].x, s);
          s = fmaf(e[r][j].y, ev[j].y, s);
          s = fmaf(e[r][j].z, ev[j].z, s);
          s = fmaf(e[r][j].w, ev[j].w, s);
        }
        float p = __expf(fmaxf(s, 0.f) - 20.f);  // fixed shift; cancels in normalize
        row[r][m] = p;
        l[r] += p;
      }
    }
#pragma unroll
    for (int r = 0; r < 4; ++r) red[r][t] = l[r];
    __syncthreads();
    for (int off = 128; off > 0; off >>= 1) {
      if (t < off) {
#pragma unroll
        for (int r = 0; r < 4; ++r) red[r][t] += red[r][t + off];
      }
      __syncthreads();
    }
    float inv[4];
#pragma unroll
    for (int r = 0; r < 4; ++r) inv[r] = 1.f / red[r][0];
    for (int m = t; m < NN; m += 256) {
#pragma unroll
      for (int r = 0; r < 4; ++r)
        A16[(size_t)(n + r) * NN + m] = f2bf(row[r][m] * inv[r]);
    }
  } else if (id < 768) {
    // ---- seg B: c transpose -> bf16 ----
    float(*ld)[68] = (float(*)[68])sbuf;
    const int idx = id - 512;
    const int m0 = (idx & 31) * 64;
    const int b = idx >> 5;
    {
      const int r = t & 63, cq = t >> 6;
      const float* cp = c + ((size_t)b * NN + m0 + r) * LL + cq * 16;
#pragma unroll
      for (int u = 0; u < 4; ++u)
        *(float4*)&ld[r][cq * 16 + 4 * u] = *(const float4*)(cp + 4 * u);
    }
    __syncthreads();
    const int o = t & 63, mq = t >> 6;
    unsigned short outv[16];
#pragma unroll
    for (int v = 0; v < 16; ++v) outv[v] = f2bf(ld[mq * 16 + v][o]);
    unsigned short* op = cT16 + ((size_t)b * LL + o) * NN + m0 + mq * 16;
    *(ushort8v*)op = *(const ushort8v*)&outv[0];
    *(ushort8v*)(op + 8) = *(const ushort8v*)&outv[8];
  } else if (id < 800) {
    // ---- seg C: Wp transpose -> fp16 ----
    float(*ld)[68] = (float(*)[68])sbuf;
    const int k0 = (id - 768) * 64;
    {
      const int r = t & 63, cq = t >> 6;
      const float* wp = Wp + (size_t)(k0 + r) * LL + cq * 16;
#pragma unroll
      for (int u = 0; u < 4; ++u)
        *(float4*)&ld[r][cq * 16 + 4 * u] = *(const float4*)(wp + 4 * u);
    }
    __syncthreads();
    const int o = t & 63, kq = t >> 6;
    halfx8 h0, h1;
#pragma unroll
    for (int v = 0; v < 8; ++v) {
      h0[v] = (half_t)ld[kq * 16 + v][o];
      h1[v] = (half_t)ld[kq * 16 + 8 + v][o];
    }
    half_t* op = WpT + (size_t)o * KT + k0 + kq * 16;
    *(halfx8*)op = h0;
    *(halfx8*)(op + 8) = h1;
  } else {
    // ---- seg D: th/thq from state (thread: row r, head h) ----
    const int idx = id - 800;
    const int n0 = (idx & 31) * 64;
    const int b = idx >> 5;
    const int r = t >> 2, h = t & 3;
    const float QS = 0.25f * 1.4426950408889634f;  // score scale + log2(e) into Q
    const float* sp = state + ((size_t)b * NN + n0 + r) * LL + h * DH;
    half_t tk[16], tq[16];
#pragma unroll
    for (int u = 0; u < 4; ++u) {
      float4 sv = *(const float4*)(sp + 4 * u);
      tk[4 * u + 0] = (half_t)sv.x; tk[4 * u + 1] = (half_t)sv.y;
      tk[4 * u + 2] = (half_t)sv.z; tk[4 * u + 3] = (half_t)sv.w;
      tq[4 * u + 0] = (half_t)(QS * sv.x); tq[4 * u + 1] = (half_t)(QS * sv.y);
      tq[4 * u + 2] = (half_t)(QS * sv.z); tq[4 * u + 3] = (half_t)(QS * sv.w);
    }
    const size_t base = ((size_t)(h * 8 + b) * NN + n0 + r) * DH;
    *(halfx8*)(th16h + base) = *(const halfx8*)&tk[0];
    *(halfx8*)(th16h + base + 8) = *(const halfx8*)&tk[8];
    *(halfx8*)(thq16h + base) = *(const halfx8*)&tq[0];
    *(halfx8*)(thq16h + base + 8) = *(const halfx8*)&tq[8];
  }
}

// ---------------- K2: cg = A @ c, 2 batches/block (A amortized), K-split x4 ----------------
__global__ __launch_bounds__(256) void k_gemm1b(const unsigned short* __restrict__ A16,
                                                const unsigned short* __restrict__ cT16,
                                                float* __restrict__ cg) {
  __shared__ unsigned short sA[64][72];
  __shared__ unsigned short sB[2][64][72];
  const int t = threadIdx.x;
  const int n0 = blockIdx.x * 64;
  const int b0 = blockIdx.y * 2;  // batch pair
  const int kh = blockIdx.z;      // 0..3
  const int wv = t >> 6, lane = t & 63;
  const int lr = lane & 15, lg = lane >> 4;
  const unsigned short* cb0 = cT16 + (size_t)b0 * LL * NN;
  const unsigned short* cb1 = cb0 + (size_t)LL * NN;
  const int sr = t >> 2, sc = (t & 3) * 16;
  f32x4 acc[2][4];
#pragma unroll
  for (int bb = 0; bb < 2; ++bb)
#pragma unroll
    for (int ot = 0; ot < 4; ++ot) acc[bb][ot] = (f32x4){0.f, 0.f, 0.f, 0.f};

  for (int k0 = kh * (NN / 4); k0 < (kh + 1) * (NN / 4); k0 += 64) {  // 8 k-tiles
    __syncthreads();
    {
      const unsigned short* ga = A16 + (size_t)(n0 + sr) * NN + k0 + sc;
      *(ushort8v*)&sA[sr][sc] = *(const ushort8v*)ga;
      *(ushort8v*)&sA[sr][sc + 8] = *(const ushort8v*)(ga + 8);
      const unsigned short* g0 = cb0 + (size_t)sr * NN + k0 + sc;
      *(ushort8v*)&sB[0][sr][sc] = *(const ushort8v*)g0;
      *(ushort8v*)&sB[0][sr][sc + 8] = *(const ushort8v*)(g0 + 8);
      const unsigned short* g1 = cb1 + (size_t)sr * NN + k0 + sc;
      *(ushort8v*)&sB[1][sr][sc] = *(const ushort8v*)g1;
      *(ushort8v*)&sB[1][sr][sc + 8] = *(const ushort8v*)(g1 + 8);
    }
    __syncthreads();
#pragma unroll
    for (int ks = 0; ks < 4; ++ks) {
      bf16x4 a = *(const bf16x4*)&sA[16 * wv + lr][ks * 16 + 4 * lg];
#pragma unroll
      for (int bb = 0; bb < 2; ++bb) {
#pragma unroll
        for (int ot = 0; ot < 4; ++ot) {
          bf16x4 bq = *(const bf16x4*)&sB[bb][ot * 16 + lr][ks * 16 + 4 * lg];
          acc[bb][ot] = MFMA16(a, bq, acc[bb][ot]);
        }
      }
    }
  }
#pragma unroll
  for (int bb = 0; bb < 2; ++bb) {
    float* outp = cg + (size_t)kh * CGSZ + ((size_t)(b0 + bb) * NN + n0 + 16 * wv) * LL;
#pragma unroll
    for (int ot = 0; ot < 4; ++ot)
#pragma unroll
      for (int reg = 0; reg < 4; ++reg)
        outp[(size_t)(4 * lg + reg) * LL + ot * 16 + lr] = acc[bb][ot][reg];
  }
}

// ---------------- K3: gcn4 — ct = tanh(sum_d E*(xg@Wp[d]) + E@bp), o-split x2, fused vt write ----------------
__global__ __launch_bounds__(256) void k_gcn4(const float* __restrict__ E,
                                              const half_t* __restrict__ WpT,
                                              const float* __restrict__ bp,
                                              const float* __restrict__ c,
                                              const float* __restrict__ cg,
                                              half_t* __restrict__ vt16h) {
  __shared__ half_t sW[32][136];  // 32 o-rows x 128 k (per d) + pad, 8.7 KB
  __shared__ float sE[64][17];
  __shared__ float sbp[16][32];
  const int t = threadIdx.x;
  const int n0 = blockIdx.x * 64;
  const int b = blockIdx.y;
  const int oh = blockIdx.z;  // o in [oh*32, oh*32+32)
  const int wv = t >> 6, lane = t & 63;
  const int lr = lane & 15, lg = lane >> 4;
  {
    const int r = t >> 2, dq = (t & 3) * 4;
    float4 ev = *(const float4*)(E + (size_t)(n0 + r) * ADA + dq);
    sE[r][dq + 0] = ev.x; sE[r][dq + 1] = ev.y;
    sE[r][dq + 2] = ev.z; sE[r][dq + 3] = ev.w;
    const int d = t >> 4, o2 = (t & 15) * 2;  // bias slice [16][32]
    float2 bv = *(const float2*)(bp + d * LL + oh * 32 + o2);
    sbp[d][o2] = bv.x;
    sbp[d][o2 + 1] = bv.y;
  }
  // x (c | sum of 4 cg partials) into registers. A-frag row = lr, k = 4*lg+j per 16-k tile.
  float xr[8][4];
  {
    const size_t rbase = ((size_t)b * NN + n0 + 16 * wv + lr) * LL;
#pragma unroll
    for (int q = 0; q < 4; ++q) {
      float4 v = *(const float4*)(c + rbase + q * 16 + 4 * lg);
      xr[q][0] = v.x; xr[q][1] = v.y; xr[q][2] = v.z; xr[q][3] = v.w;
    }
#pragma unroll
    for (int q = 0; q < 4; ++q) {
      float4 s0 = *(const float4*)(cg + rbase + q * 16 + 4 * lg);
      float4 s1 = *(const float4*)(cg + CGSZ + rbase + q * 16 + 4 * lg);
      float4 s2 = *(const float4*)(cg + 2 * CGSZ + rbase + q * 16 + 4 * lg);
      float4 s3 = *(const float4*)(cg + 3 * CGSZ + rbase + q * 16 + 4 * lg);
      xr[4 + q][0] = (s0.x + s1.x) + (s2.x + s3.x);
      xr[4 + q][1] = (s0.y + s1.y) + (s2.y + s3.y);
      xr[4 + q][2] = (s0.z + s1.z) + (s2.z + s3.z);
      xr[4 + q][3] = (s0.w + s1.w) + (s2.w + s3.w);
    }
  }
  __syncthreads();
  // acc init with bias; D rows = 16wv+4lg+reg (n), cols = ot2*16+lr (o local)
  f32x4 acc[2];
#pragma unroll
  for (int ot2 = 0; ot2 < 2; ++ot2) {
    f32x4 s = (f32x4){0.f, 0.f, 0.f, 0.f};
#pragma unroll
    for (int d = 0; d < ADA; ++d) {
      const float bpv = sbp[d][ot2 * 16 + lr];
#pragma unroll
      for (int reg = 0; reg < 4; ++reg)
        s[reg] = fmaf(sE[16 * wv + 4 * lg + reg][d], bpv, s[reg]);
    }
    acc[ot2] = s;
  }
  // W staging: thread covers o-row so (0..31), 16-half chunk sq (0..7)
  const int so = t >> 3, sq = t & 7;
  halfx8 wreg[2];
  {
    const half_t* p = WpT + (size_t)(oh * 32 + so) * KT + sq * 16;
    wreg[0] = *(const halfx8*)p;
    wreg[1] = *(const halfx8*)(p + 8);
  }
  for (int dd = 0; dd < ADA; ++dd) {
    __syncthreads();  // previous iteration's MFMAs done with sW
    *(halfx8*)&sW[so][sq * 16] = wreg[0];
    *(halfx8*)&sW[so][sq * 16 + 8] = wreg[1];
    __syncthreads();  // sW ready
    if (dd < ADA - 1) {
      const half_t* p = WpT + (size_t)(oh * 32 + so) * KT + (dd + 1) * 128 + sq * 16;
      wreg[0] = *(const halfx8*)p;
      wreg[1] = *(const halfx8*)(p + 8);
    }
    const float e = sE[16 * wv + lr][dd];
    halfx4 af[8];
#pragma unroll
    for (int kt = 0; kt < 8; ++kt)
#pragma unroll
      for (int j = 0; j < 4; ++j) af[kt][j] = (half_t)(e * xr[kt][j]);
#pragma unroll
    for (int kt = 0; kt < 8; ++kt) {
#pragma unroll
      for (int ot2 = 0; ot2 < 2; ++ot2) {
        halfx4 bq = *(const halfx4*)&sW[ot2 * 16 + lr][kt * 16 + 4 * lg];
        acc[ot2] = MFMA16H(af[kt], bq, acc[ot2]);
      }
    }
  }
  // epilogue: tanh + direct transposed fp16 store to vt16h[hb][d=lr][n]
#pragma unroll
  for (int ot2 = 0; ot2 < 2; ++ot2) {
    const int h = oh * 2 + ot2;
    halfx4 o4;
#pragma unroll
    for (int reg = 0; reg < 4; ++reg) o4[reg] = (half_t)tanh_fast(acc[ot2][reg]);
    *(halfx4*)(vt16h + ((size_t)(h * 8 + b) * DH + lr) * NN + n0 + 16 * wv + 4 * lg) = o4;
  }
}

// ---------------- K4: fp16 MFMA attention — 128 q/block (8 frags/wave), m split 8-way ----------------
__global__ __launch_bounds__(512, 4) void k_attn5(const half_t* __restrict__ th16h,
                                                  const half_t* __restrict__ thq16h,
                                                  const half_t* __restrict__ vt16h,
                                                  float* __restrict__ out) {
  __shared__ float sred[8][8][16][16];  // 64 KB: phase A den (first 4 KB), phase B num
  float* dfl = &sred[0][0][0][0];
  const int hb = blockIdx.x;
  const int h = hb >> 3, b = hb & 7;
  const int wv = threadIdx.x >> 6, lane = threadIdx.x & 63;
  const int q0 = blockIdx.y * 128;
  const int lr = lane & 15, lg = lane >> 4;
  const half_t* th = th16h + (size_t)hb * NN * DH;
  const half_t* thq = thq16h + (size_t)hb * NN * DH;
  const half_t* vrow = vt16h + ((size_t)hb * DH + lr) * NN;  // V^T row d=lr
  halfx4 qf[8];
#pragma unroll
  for (int f = 0; f < 8; ++f)
    qf[f] = *(const halfx4*)(thq + (size_t)(q0 + 16 * f + lr) * DH + 4 * lg);
  // shift-8 softmax via MFMA C-init (fp16-safe, cancels in num/den)
  const float SH = 8.f * 1.4426950408889634f;
  const f32x4 shiftv = {-SH, -SH, -SH, -SH};
  f32x4 acc[8];
  float den[8];
#pragma unroll
  for (int f = 0; f < 8; ++f) { acc[f] = (f32x4){0.f, 0.f, 0.f, 0.f}; den[f] = 0.f; }

  const int mb = wv * (NN / 8);  // this wave's 256-row m-slice
  halfx4 kf = *(const halfx4*)(th + (size_t)(mb + lr) * DH + 4 * lg);
  halfx4 vf = *(const halfx4*)(vrow + mb + 4 * lg);
  for (int mt = 0; mt < NN / 128; ++mt) {  // 16 tiles of 16
    halfx4 kf_n = kf, vf_n = vf;
    if (mt < NN / 128 - 1) {
      const int mn = mb + (mt + 1) * 16;
      kf_n = *(const halfx4*)(th + (size_t)(mn + lr) * DH + 4 * lg);
      vf_n = *(const halfx4*)(vrow + mn + 4 * lg);
    }
#pragma unroll
    for (int f = 0; f < 8; ++f) {
      f32x4 s = MFMA16H(kf, qf[f], shiftv);  // lane: col q, rows m; pre-shifted
      float p0 = EXP2F(s[0]), p1 = EXP2F(s[1]), p2 = EXP2F(s[2]), p3 = EXP2F(s[3]);
      den[f] += (p0 + p1) + (p2 + p3);
      halfx2 lo = cvt_pk2(p0, p1), hi = cvt_pk2(p2, p3);
      halfx4 pf;
      pf[0] = lo[0]; pf[1] = lo[1]; pf[2] = hi[0]; pf[3] = hi[1];
      acc[f] = MFMA16H(pf, vf, acc[f]);  // lane: col d=lr, rows q=16f+4lg+reg
    }
    kf = kf_n; vf = vf_n;
  }
#pragma unroll
  for (int f = 0; f < 8; ++f) {
    den[f] += __shfl_xor(den[f], 16);
    den[f] += __shfl_xor(den[f], 32);
  }
  // phase A: den partials (8 waves x 8 frags x 16 q = 4 KB of sred)
  if (lane < 16) {
#pragma unroll
    for (int f = 0; f < 8; ++f) dfl[(wv * 8 + f) * 16 + lane] = den[f];
  }
  __syncthreads();
  const int t = threadIdx.x;
  const int fo = t >> 6, ro = (t >> 2) & 15, duo = (t & 3) * 4;
  float ds = 0.f;
#pragma unroll
  for (int w = 0; w < 8; ++w) ds += dfl[(w * 8 + fo) * 16 + ro];
  __syncthreads();  // done reading den region before overwrite
  // phase B: numerator partials
#pragma unroll
  for (int f = 0; f < 8; ++f) {
#pragma unroll
    for (int reg = 0; reg < 4; ++reg) sred[wv][f][4 * lg + reg][lr] = acc[f][reg];
  }
  __syncthreads();
  float4 ns = make_float4(0.f, 0.f, 0.f, 0.f);
#pragma unroll
  for (int w = 0; w < 8; ++w) {
    float4 v = *(const float4*)&sred[w][fo][ro][duo];
    ns.x += v.x; ns.y += v.y; ns.z += v.z; ns.w += v.w;
  }
  const float inv = -1.f / ds;
  float4 o = make_float4(ns.x * inv, ns.y * inv, ns.z * inv, ns.w * inv);
  *(float4*)(out + ((size_t)b * NN + q0 + 16 * fo + ro) * LL + h * DH + duo) = o;
}

extern "C" void kernel_launch(void* const* d_in, const int* in_sizes, int n_in,
                              void* d_out, int out_size, void* d_ws, size_t ws_size,
                              hipStream_t stream) {
  const float* c = (const float*)d_in[0];
  const float* state = (const float*)d_in[3];
  const float* E = (const float*)d_in[4];
  const float* Wp = (const float*)d_in[13];
  const float* bp = (const float*)d_in[14];
  float* out = (float*)d_out;

  unsigned short* A16 = (unsigned short*)d_ws;        // 2048*2048 bf16 = 8 MB
  unsigned short* cT16 = A16 + (size_t)NN * NN;       // 2 MB
  half_t* WpT = (half_t*)(cT16 + (size_t)BB * LL * NN);  // 256 KB
  float* cg = (float*)(WpT + (size_t)LL * KT);        // 4 x 4 MB partials
  half_t* th16h = (half_t*)(cg + 4 * CGSZ);           // 2 MB
  half_t* thq16h = th16h + (size_t)HB * NN * DH;      // 2 MB
  half_t* vt16h = thq16h + (size_t)HB * NN * DH;      // 2 MB

  k_preps<<<1056, 256, 0, stream>>>(E, c, state, Wp, A16, cT16, WpT, th16h, thq16h);
  k_gemm1b<<<dim3(NN / 64, BB / 2, 4), 256, 0, stream>>>(A16, cT16, cg);
  k_gcn4<<<dim3(NN / 64, BB, 2), 256, 0, stream>>>(E, WpT, bp, c, cg, vt16h);
  k_attn5<<<dim3(HB, NN / 128), 512, 0, stream>>>(th16h, thq16h, vt16h, out);
}

// Round 18
// 67.857 us; speedup vs baseline: 1.2561x; 1.0844x over previous
//
#include <hip/hip_runtime.h>
#include <hip/hip_bf16.h>

#define NN 2048
#define BB 8
#define LL 64
#define ADA 16
#define DH 16
#define HB 32
#define KT 2048   // GCN GEMM total K = ADA*2*LL
#define CGSZ ((size_t)BB * NN * LL)  // one cg partial buffer

typedef __attribute__((ext_vector_type(4))) short bf16x4;
typedef __attribute__((ext_vector_type(4))) float f32x4;
typedef _Float16 half_t;
typedef __attribute__((ext_vector_type(2))) _Float16 halfx2;
typedef __attribute__((ext_vector_type(4))) _Float16 halfx4;
typedef __attribute__((ext_vector_type(8))) _Float16 halfx8;

// __has_builtin(__builtin_amdgcn_mfma_*) is FALSE on the host pass of hipcc's
// dual compile -> guard with __HIP_DEVICE_COMPILE__, parse-only dummy on host.
#if defined(__HIP_DEVICE_COMPILE__)
#if __has_builtin(__builtin_amdgcn_mfma_f32_16x16x16f16)
#define MFMA16H(a, b, c) __builtin_amdgcn_mfma_f32_16x16x16f16(a, b, c, 0, 0, 0)
#elif __has_builtin(__builtin_amdgcn_mfma_f32_16x16x16_f16)
#define MFMA16H(a, b, c) __builtin_amdgcn_mfma_f32_16x16x16_f16(a, b, c, 0, 0, 0)
#else
#error "no 16x16x16 f16 mfma builtin on device"
#endif
#if __has_builtin(__builtin_amdgcn_mfma_f32_16x16x32_f16)
#define MFMA32H(a, b, c) __builtin_amdgcn_mfma_f32_16x16x32_f16(a, b, c, 0, 0, 0)
#else
#error "no 16x16x32 f16 mfma builtin on device"
#endif
#if __has_builtin(__builtin_amdgcn_exp2f)
#define EXP2F(x) __builtin_amdgcn_exp2f(x)
#else
#define EXP2F(x) exp2f(x)
#endif
#else
#define MFMA16H(a, b, c) (c)
#define MFMA32H(a, b, c) (c)
#define EXP2F(x) exp2f(x)
#endif

__device__ inline halfx2 cvt_pk2(float a, float b) {
#if defined(__HIP_DEVICE_COMPILE__) && __has_builtin(__builtin_amdgcn_cvt_pkrtz)
  auto r = __builtin_amdgcn_cvt_pkrtz(a, b);
  return __builtin_bit_cast(halfx2, r);
#else
  halfx2 r;
  r[0] = (_Float16)a;
  r[1] = (_Float16)b;
  return r;
#endif
}

__device__ inline float tanh_fast(float v) {
  return 1.f - 2.f / (__expf(2.f * v) + 1.f);
}

// ---------------- K1: fused prep über-kernel (4 independent segments) ----------------
__global__ __launch_bounds__(256) void k_preps(const float* __restrict__ E,
                                               const float* __restrict__ c,
                                               const float* __restrict__ state,
                                               const float* __restrict__ Wp,
                                               half_t* __restrict__ A16,
                                               half_t* __restrict__ cT16,
                                               half_t* __restrict__ WpT,
                                               half_t* __restrict__ th16h,
                                               half_t* __restrict__ thq16h) {
  __shared__ float sbuf[4 * 2304];  // 36,864 B union
  const int id = blockIdx.x;
  const int t = threadIdx.x;
  if (id < 512) {
    // ---- seg A: rowsoftmax, 4 rows, fp16 out ----
    float(*row)[NN] = (float(*)[NN])sbuf;
    float(*red)[256] = (float(*)[256])(sbuf + 4 * NN);
    const int n = id * 4;
    float4 e[4][4];
#pragma unroll
    for (int r = 0; r < 4; ++r) {
      const float4* Er = (const float4*)(E + (size_t)(n + r) * ADA);
#pragma unroll
      for (int j = 0; j < 4; ++j) e[r][j] = Er[j];
    }
    float l[4] = {0.f, 0.f, 0.f, 0.f};
    for (int m = t; m < NN; m += 256) {
      const float4* Em = (const float4*)(E + (size_t)m * ADA);
      float4 ev[4];
#pragma unroll
      for (int j = 0; j < 4; ++j) ev[j] = Em[j];
#pragma unroll
      for (int r = 0; r < 4; ++r) {
        float s = 0.f;
#pragma unroll
        for (int j = 0; j < 4; ++j) {
          s = fmaf(e[r][j].x, ev[j].x, s);
          s = fmaf(e[r][j].y, ev[j].y, s);
          s = fmaf(e[r][j].z, ev[j].z, s);
          s = fmaf(e[r][j].w, ev[j].w, s);
        }
        float p = __expf(fmaxf(s, 0.f) - 20.f);  // fixed shift; cancels in normalize
        row[r][m] = p;
        l[r] += p;
      }
    }
#pragma unroll
    for (int r = 0; r < 4; ++r) red[r][t] = l[r];
    __syncthreads();
    for (int off = 128; off > 0; off >>= 1) {
      if (t < off) {
#pragma unroll
        for (int r = 0; r < 4; ++r) red[r][t] += red[r][t + off];
      }
      __syncthreads();
    }
    float inv[4];
#pragma unroll
    for (int r = 0; r < 4; ++r) inv[r] = 1.f / red[r][0];
    for (int m = t; m < NN; m += 256) {
#pragma unroll
      for (int r = 0; r < 4; ++r)
        A16[(size_t)(n + r) * NN + m] = (half_t)(row[r][m] * inv[r]);
    }
  } else if (id < 768) {
    // ---- seg B: c transpose -> fp16 ----
    float(*ld)[68] = (float(*)[68])sbuf;
    const int idx = id - 512;
    const int m0 = (idx & 31) * 64;
    const int b = idx >> 5;
    {
      const int r = t & 63, cq = t >> 6;
      const float* cp = c + ((size_t)b * NN + m0 + r) * LL + cq * 16;
#pragma unroll
      for (int u = 0; u < 4; ++u)
        *(float4*)&ld[r][cq * 16 + 4 * u] = *(const float4*)(cp + 4 * u);
    }
    __syncthreads();
    const int o = t & 63, mq = t >> 6;
    halfx8 h0, h1;
#pragma unroll
    for (int v = 0; v < 8; ++v) {
      h0[v] = (half_t)ld[mq * 16 + v][o];
      h1[v] = (half_t)ld[mq * 16 + 8 + v][o];
    }
    half_t* op = cT16 + ((size_t)b * LL + o) * NN + m0 + mq * 16;
    *(halfx8*)op = h0;
    *(halfx8*)(op + 8) = h1;
  } else if (id < 800) {
    // ---- seg C: Wp transpose -> fp16 ----
    float(*ld)[68] = (float(*)[68])sbuf;
    const int k0 = (id - 768) * 64;
    {
      const int r = t & 63, cq = t >> 6;
      const float* wp = Wp + (size_t)(k0 + r) * LL + cq * 16;
#pragma unroll
      for (int u = 0; u < 4; ++u)
        *(float4*)&ld[r][cq * 16 + 4 * u] = *(const float4*)(wp + 4 * u);
    }
    __syncthreads();
    const int o = t & 63, kq = t >> 6;
    halfx8 h0, h1;
#pragma unroll
    for (int v = 0; v < 8; ++v) {
      h0[v] = (half_t)ld[kq * 16 + v][o];
      h1[v] = (half_t)ld[kq * 16 + 8 + v][o];
    }
    half_t* op = WpT + (size_t)o * KT + k0 + kq * 16;
    *(halfx8*)op = h0;
    *(halfx8*)(op + 8) = h1;
  } else {
    // ---- seg D: th/thq from state (thread: row r, head h) ----
    const int idx = id - 800;
    const int n0 = (idx & 31) * 64;
    const int b = idx >> 5;
    const int r = t >> 2, h = t & 3;
    const float QS = 0.25f * 1.4426950408889634f;  // score scale + log2(e) into Q
    const float* sp = state + ((size_t)b * NN + n0 + r) * LL + h * DH;
    half_t tk[16], tq[16];
#pragma unroll
    for (int u = 0; u < 4; ++u) {
      float4 sv = *(const float4*)(sp + 4 * u);
      tk[4 * u + 0] = (half_t)sv.x; tk[4 * u + 1] = (half_t)sv.y;
      tk[4 * u + 2] = (half_t)sv.z; tk[4 * u + 3] = (half_t)sv.w;
      tq[4 * u + 0] = (half_t)(QS * sv.x); tq[4 * u + 1] = (half_t)(QS * sv.y);
      tq[4 * u + 2] = (half_t)(QS * sv.z); tq[4 * u + 3] = (half_t)(QS * sv.w);
    }
    const size_t base = ((size_t)(h * 8 + b) * NN + n0 + r) * DH;
    *(halfx8*)(th16h + base) = *(const halfx8*)&tk[0];
    *(halfx8*)(th16h + base + 8) = *(const halfx8*)&tk[8];
    *(halfx8*)(thq16h + base) = *(const halfx8*)&tq[0];
    *(halfx8*)(thq16h + base + 8) = *(const halfx8*)&tq[8];
  }
}

// ---------------- K2: cg = A @ c, 2 batches/block, K-split x4, fp16 K=32 MFMA ----------------
__global__ __launch_bounds__(256) void k_gemm1b(const half_t* __restrict__ A16,
                                                const half_t* __restrict__ cT16,
                                                float* __restrict__ cg) {
  __shared__ half_t sA[64][72];
  __shared__ half_t sB[2][64][72];
  const int t = threadIdx.x;
  const int n0 = blockIdx.x * 64;
  const int b0 = blockIdx.y * 2;  // batch pair
  const int kh = blockIdx.z;      // 0..3
  const int wv = t >> 6, lane = t & 63;
  const int lr = lane & 15, lg = lane >> 4;
  const half_t* cb0 = cT16 + (size_t)b0 * LL * NN;
  const half_t* cb1 = cb0 + (size_t)LL * NN;
  const int sr = t >> 2, sc = (t & 3) * 16;
  f32x4 acc[2][4];
#pragma unroll
  for (int bb = 0; bb < 2; ++bb)
#pragma unroll
    for (int ot = 0; ot < 4; ++ot) acc[bb][ot] = (f32x4){0.f, 0.f, 0.f, 0.f};

  for (int k0 = kh * (NN / 4); k0 < (kh + 1) * (NN / 4); k0 += 64) {  // 8 k-tiles
    __syncthreads();
    {
      const half_t* ga = A16 + (size_t)(n0 + sr) * NN + k0 + sc;
      *(halfx8*)&sA[sr][sc] = *(const halfx8*)ga;
      *(halfx8*)&sA[sr][sc + 8] = *(const halfx8*)(ga + 8);
      const half_t* g0 = cb0 + (size_t)sr * NN + k0 + sc;
      *(halfx8*)&sB[0][sr][sc] = *(const halfx8*)g0;
      *(halfx8*)&sB[0][sr][sc + 8] = *(const halfx8*)(g0 + 8);
      const half_t* g1 = cb1 + (size_t)sr * NN + k0 + sc;
      *(halfx8*)&sB[1][sr][sc] = *(const halfx8*)g1;
      *(halfx8*)&sB[1][sr][sc + 8] = *(const halfx8*)(g1 + 8);
    }
    __syncthreads();
#pragma unroll
    for (int kt = 0; kt < 2; ++kt) {  // K=32 per MFMA
      halfx8 a = *(const halfx8*)&sA[16 * wv + lr][kt * 32 + 8 * lg];
#pragma unroll
      for (int bb = 0; bb < 2; ++bb) {
#pragma unroll
        for (int ot = 0; ot < 4; ++ot) {
          halfx8 bq = *(const halfx8*)&sB[bb][ot * 16 + lr][kt * 32 + 8 * lg];
          acc[bb][ot] = MFMA32H(a, bq, acc[bb][ot]);
        }
      }
    }
  }
#pragma unroll
  for (int bb = 0; bb < 2; ++bb) {
    float* outp = cg + (size_t)kh * CGSZ + ((size_t)(b0 + bb) * NN + n0 + 16 * wv) * LL;
#pragma unroll
    for (int ot = 0; ot < 4; ++ot)
#pragma unroll
      for (int reg = 0; reg < 4; ++reg)
        outp[(size_t)(4 * lg + reg) * LL + ot * 16 + lr] = acc[bb][ot][reg];
  }
}

// ---------------- K3: gcn4 — ct = tanh(sum_d E*(xg@Wp[d]) + E@bp), K=32 MFMA, fused vt write ----------------
__global__ __launch_bounds__(256) void k_gcn4(const float* __restrict__ E,
                                              const half_t* __restrict__ WpT,
                                              const float* __restrict__ bp,
                                              const float* __restrict__ c,
                                              const float* __restrict__ cg,
                                              half_t* __restrict__ vt16h) {
  __shared__ half_t sW[32][136];  // 32 o-rows x 128 k (per d) + pad, 8.7 KB
  __shared__ float sE[64][17];
  __shared__ float sbp[16][32];
  const int t = threadIdx.x;
  const int n0 = blockIdx.x * 64;
  const int b = blockIdx.y;
  const int oh = blockIdx.z;  // o in [oh*32, oh*32+32)
  const int wv = t >> 6, lane = t & 63;
  const int lr = lane & 15, lg = lane >> 4;
  {
    const int r = t >> 2, dq = (t & 3) * 4;
    float4 ev = *(const float4*)(E + (size_t)(n0 + r) * ADA + dq);
    sE[r][dq + 0] = ev.x; sE[r][dq + 1] = ev.y;
    sE[r][dq + 2] = ev.z; sE[r][dq + 3] = ev.w;
    const int d = t >> 4, o2 = (t & 15) * 2;  // bias slice [16][32]
    float2 bv = *(const float2*)(bp + d * LL + oh * 32 + o2);
    sbp[d][o2] = bv.x;
    sbp[d][o2 + 1] = bv.y;
  }
  // x (c | sum of 4 cg partials) into registers. K=32 A-frag: row=lr, k = kt*32+8lg+j.
  float xr[4][8];
  {
    const size_t rbase = ((size_t)b * NN + n0 + 16 * wv + lr) * LL;
#pragma unroll
    for (int u = 0; u < 2; ++u) {  // kappa=0 (c): kt = u
      const float* p = c + rbase + u * 32 + 8 * lg;
      float4 v0 = *(const float4*)p, v1 = *(const float4*)(p + 4);
      xr[u][0] = v0.x; xr[u][1] = v0.y; xr[u][2] = v0.z; xr[u][3] = v0.w;
      xr[u][4] = v1.x; xr[u][5] = v1.y; xr[u][6] = v1.z; xr[u][7] = v1.w;
    }
#pragma unroll
    for (int u = 0; u < 2; ++u) {  // kappa=1 (cg sum): kt = 2+u
      const size_t off = rbase + u * 32 + 8 * lg;
      float4 a0 = *(const float4*)(cg + off), a1 = *(const float4*)(cg + off + 4);
      float4 b0 = *(const float4*)(cg + CGSZ + off), b1 = *(const float4*)(cg + CGSZ + off + 4);
      float4 c0 = *(const float4*)(cg + 2 * CGSZ + off), c1 = *(const float4*)(cg + 2 * CGSZ + off + 4);
      float4 d0 = *(const float4*)(cg + 3 * CGSZ + off), d1 = *(const float4*)(cg + 3 * CGSZ + off + 4);
      xr[2 + u][0] = (a0.x + b0.x) + (c0.x + d0.x);
      xr[2 + u][1] = (a0.y + b0.y) + (c0.y + d0.y);
      xr[2 + u][2] = (a0.z + b0.z) + (c0.z + d0.z);
      xr[2 + u][3] = (a0.w + b0.w) + (c0.w + d0.w);
      xr[2 + u][4] = (a1.x + b1.x) + (c1.x + d1.x);
      xr[2 + u][5] = (a1.y + b1.y) + (c1.y + d1.y);
      xr[2 + u][6] = (a1.z + b1.z) + (c1.z + d1.z);
      xr[2 + u][7] = (a1.w + b1.w) + (c1.w + d1.w);
    }
  }
  __syncthreads();
  // acc init with bias; D rows = 16wv+4lg+reg (n), cols = ot2*16+lr (o local)
  f32x4 acc[2];
#pragma unroll
  for (int ot2 = 0; ot2 < 2; ++ot2) {
    f32x4 s = (f32x4){0.f, 0.f, 0.f, 0.f};
#pragma unroll
    for (int d = 0; d < ADA; ++d) {
      const float bpv = sbp[d][ot2 * 16 + lr];
#pragma unroll
      for (int reg = 0; reg < 4; ++reg)
        s[reg] = fmaf(sE[16 * wv + 4 * lg + reg][d], bpv, s[reg]);
    }
    acc[ot2] = s;
  }
  // W staging: thread covers o-row so (0..31), 16-half chunk sq (0..7)
  const int so = t >> 3, sq = t & 7;
  halfx8 wreg[2];
  {
    const half_t* p = WpT + (size_t)(oh * 32 + so) * KT + sq * 16;
    wreg[0] = *(const halfx8*)p;
    wreg[1] = *(const halfx8*)(p + 8);
  }
  for (int dd = 0; dd < ADA; ++dd) {
    __syncthreads();  // previous iteration's MFMAs done with sW
    *(halfx8*)&sW[so][sq * 16] = wreg[0];
    *(halfx8*)&sW[so][sq * 16 + 8] = wreg[1];
    __syncthreads();  // sW ready
    if (dd < ADA - 1) {
      const half_t* p = WpT + (size_t)(oh * 32 + so) * KT + (dd + 1) * 128 + sq * 16;
      wreg[0] = *(const halfx8*)p;
      wreg[1] = *(const halfx8*)(p + 8);
    }
    const float e = sE[16 * wv + lr][dd];
    halfx8 af[4];
#pragma unroll
    for (int kt = 0; kt < 4; ++kt)
#pragma unroll
      for (int j = 0; j < 8; ++j) af[kt][j] = (half_t)(e * xr[kt][j]);
#pragma unroll
    for (int kt = 0; kt < 4; ++kt) {
#pragma unroll
      for (int ot2 = 0; ot2 < 2; ++ot2) {
        halfx8 bq = *(const halfx8*)&sW[ot2 * 16 + lr][kt * 32 + 8 * lg];
        acc[ot2] = MFMA32H(af[kt], bq, acc[ot2]);
      }
    }
  }
  // epilogue: tanh + direct transposed fp16 store to vt16h[hb][d=lr][n]
#pragma unroll
  for (int ot2 = 0; ot2 < 2; ++ot2) {
    const int h = oh * 2 + ot2;
    halfx4 o4;
#pragma unroll
    for (int reg = 0; reg < 4; ++reg) o4[reg] = (half_t)tanh_fast(acc[ot2][reg]);
    *(halfx4*)(vt16h + ((size_t)(h * 8 + b) * DH + lr) * NN + n0 + 16 * wv + 4 * lg) = o4;
  }
}

// ---------------- K4: fp16 MFMA attention — 128 q/block (8 frags/wave), m split 8-way ----------------
__global__ __launch_bounds__(512, 4) void k_attn5(const half_t* __restrict__ th16h,
                                                  const half_t* __restrict__ thq16h,
                                                  const half_t* __restrict__ vt16h,
                                                  float* __restrict__ out) {
  __shared__ float sred[8][8][16][16];  // 64 KB: phase A den (first 4 KB), phase B num
  float* dfl = &sred[0][0][0][0];
  const int hb = blockIdx.x;
  const int h = hb >> 3, b = hb & 7;
  const int wv = threadIdx.x >> 6, lane = threadIdx.x & 63;
  const int q0 = blockIdx.y * 128;
  const int lr = lane & 15, lg = lane >> 4;
  const half_t* th = th16h + (size_t)hb * NN * DH;
  const half_t* thq = thq16h + (size_t)hb * NN * DH;
  const half_t* vrow = vt16h + ((size_t)hb * DH + lr) * NN;  // V^T row d=lr
  halfx4 qf[8];
#pragma unroll
  for (int f = 0; f < 8; ++f)
    qf[f] = *(const halfx4*)(thq + (size_t)(q0 + 16 * f + lr) * DH + 4 * lg);
  // shift-8 softmax via MFMA C-init (fp16-safe, cancels in num/den)
  const float SH = 8.f * 1.4426950408889634f;
  const f32x4 shiftv = {-SH, -SH, -SH, -SH};
  f32x4 acc[8];
  float den[8];
#pragma unroll
  for (int f = 0; f < 8; ++f) { acc[f] = (f32x4){0.f, 0.f, 0.f, 0.f}; den[f] = 0.f; }

  const int mb = wv * (NN / 8);  // this wave's 256-row m-slice
  halfx4 kf = *(const halfx4*)(th + (size_t)(mb + lr) * DH + 4 * lg);
  halfx4 vf = *(const halfx4*)(vrow + mb + 4 * lg);
  for (int mt = 0; mt < NN / 128; ++mt) {  // 16 tiles of 16
    halfx4 kf_n = kf, vf_n = vf;
    if (mt < NN / 128 - 1) {
      const int mn = mb + (mt + 1) * 16;
      kf_n = *(const halfx4*)(th + (size_t)(mn + lr) * DH + 4 * lg);
      vf_n = *(const halfx4*)(vrow + mn + 4 * lg);
    }
#pragma unroll
    for (int f = 0; f < 8; ++f) {
      f32x4 s = MFMA16H(kf, qf[f], shiftv);  // lane: col q, rows m; pre-shifted
      float p0 = EXP2F(s[0]), p1 = EXP2F(s[1]), p2 = EXP2F(s[2]), p3 = EXP2F(s[3]);
      den[f] += (p0 + p1) + (p2 + p3);
      halfx2 lo = cvt_pk2(p0, p1), hi = cvt_pk2(p2, p3);
      halfx4 pf;
      pf[0] = lo[0]; pf[1] = lo[1]; pf[2] = hi[0]; pf[3] = hi[1];
      acc[f] = MFMA16H(pf, vf, acc[f]);  // lane: col d=lr, rows q=16f+4lg+reg
    }
    kf = kf_n; vf = vf_n;
  }
#pragma unroll
  for (int f = 0; f < 8; ++f) {
    den[f] += __shfl_xor(den[f], 16);
    den[f] += __shfl_xor(den[f], 32);
  }
  // phase A: den partials (8 waves x 8 frags x 16 q = 4 KB of sred)
  if (lane < 16) {
#pragma unroll
    for (int f = 0; f < 8; ++f) dfl[(wv * 8 + f) * 16 + lane] = den[f];
  }
  __syncthreads();
  const int t = threadIdx.x;
  const int fo = t >> 6, ro = (t >> 2) & 15, duo = (t & 3) * 4;
  float ds = 0.f;
#pragma unroll
  for (int w = 0; w < 8; ++w) ds += dfl[(w * 8 + fo) * 16 + ro];
  __syncthreads();  // done reading den region before overwrite
  // phase B: numerator partials
#pragma unroll
  for (int f = 0; f < 8; ++f) {
#pragma unroll
    for (int reg = 0; reg < 4; ++reg) sred[wv][f][4 * lg + reg][lr] = acc[f][reg];
  }
  __syncthreads();
  float4 ns = make_float4(0.f, 0.f, 0.f, 0.f);
#pragma unroll
  for (int w = 0; w < 8; ++w) {
    float4 v = *(const float4*)&sred[w][fo][ro][duo];
    ns.x += v.x; ns.y += v.y; ns.z += v.z; ns.w += v.w;
  }
  const float inv = -1.f / ds;
  float4 o = make_float4(ns.x * inv, ns.y * inv, ns.z * inv, ns.w * inv);
  *(float4*)(out + ((size_t)b * NN + q0 + 16 * fo + ro) * LL + h * DH + duo) = o;
}

extern "C" void kernel_launch(void* const* d_in, const int* in_sizes, int n_in,
                              void* d_out, int out_size, void* d_ws, size_t ws_size,
                              hipStream_t stream) {
  const float* c = (const float*)d_in[0];
  const float* state = (const float*)d_in[3];
  const float* E = (const float*)d_in[4];
  const float* Wp = (const float*)d_in[13];
  const float* bp = (const float*)d_in[14];
  float* out = (float*)d_out;

  half_t* A16 = (half_t*)d_ws;                        // 2048*2048 fp16 = 8 MB
  half_t* cT16 = A16 + (size_t)NN * NN;               // 2 MB
  half_t* WpT = cT16 + (size_t)BB * LL * NN;          // 256 KB
  float* cg = (float*)(WpT + (size_t)LL * KT);        // 4 x 4 MB partials
  half_t* th16h = (half_t*)(cg + 4 * CGSZ);           // 2 MB
  half_t* thq16h = th16h + (size_t)HB * NN * DH;      // 2 MB
  half_t* vt16h = thq16h + (size_t)HB * NN * DH;      // 2 MB

  k_preps<<<1056, 256, 0, stream>>>(E, c, state, Wp, A16, cT16, WpT, th16h, thq16h);
  k_gemm1b<<<dim3(NN / 64, BB / 2, 4), 256, 0, stream>>>(A16, cT16, cg);
  k_gcn4<<<dim3(NN / 64, BB, 2), 256, 0, stream>>>(E, WpT, bp, c, cg, vt16h);
  k_attn5<<<dim3(HB, NN / 128), 512, 0, stream>>>(th16h, thq16h, vt16h, out);
}